// Round 6
// baseline (123.315 us; speedup 1.0000x reference)
//
#include <hip/hip_runtime.h>
#include <stdint.h>

// kNN: B=2, N=2048, D=16, K=16. Output (B,N,K,2) int32: [batch_idx, neighbor_idx].
//
// Bit-exact vs numpy f32 reference — ONLY via named intrinsics
// (__fmul_rn/__fadd_rn/__fsqrt_rn), which are opaque to -ffp-contract=fast
// and reassociation. R5 FAILED (absmax 1198) because plain +/* on vector
// floats got contracted/reassociated, perturbing the pairwise-sum tree and
// swapping near-tie neighbor ranks. Do NOT use plain FP operators here.
//  - numpy pairwise-sum tree n=16: r[j]=s[j]+s[j+8]; ((r0+r1)+(r2+r3))+((r4+r5)+(r6+r7))
//  - __fsqrt_rn == np.sqrt (correctly rounded). sqrt REQUIRED for tie order.
//  - key = (dist_bits<<32)|idx : monotone, ties -> lower index (stable top_k).
//  - self (c==n, dist==0, unique global min) masked to ~0 pre-selection ==
//    reference's [:, :, 1:] slice; 16 pop rounds, pop r == output rank r.
//
// R6 structure (= R5 structure, R1-R4 math):
//  - 1 wave = 1 query; 128-thread blocks = 2 independent queries. NO LDS,
//    NO barriers, no merge phase. 32 candidates/lane -> 32 u64 keys in VGPRs.
//  - __launch_bounds__(128, 2): 256-VGPR budget so keys stay in real VGPRs
//    (R4's 128-cap caused AGPR shuffling: VGPR_Count=36, VALUBusy up, no gain).
//  - 4 sorted runs of 8 (Batcher), 16 pop rounds: local 4-head argmin + DPP
//    wave-min (row_shr 1/2/4/8 + row_bcast 15/31 + readlane 63, validated R4)
//    + winner-lane run shift. Winner lane writes int2 output directly.

#define NPTS 2048
#define DIMS 16
#define KK 16
#define THREADS 128            // 2 waves = 2 independent queries per block
#define CPL 32                 // candidates per lane (2048 / 64)

__device__ __forceinline__ void ce(uint64_t& a, uint64_t& b) {
    uint64_t lo = (a < b) ? a : b;
    uint64_t hi = (a < b) ? b : a;
    a = lo; b = hi;
}

// 64-lane u64 min-reduce via DPP; result broadcast to all lanes via readlane.
// (bit-validated in R4: absmax=0)
__device__ __forceinline__ uint64_t wave_min_u64(uint64_t v) {
    uint32_t lo = (uint32_t)v;
    uint32_t hi = (uint32_t)(v >> 32);
#define DPP_STEP(CTRL, RMASK)                                                   \
    {                                                                           \
        uint32_t slo = (uint32_t)__builtin_amdgcn_update_dpp(                   \
            -1, (int)lo, (CTRL), (RMASK), 0xF, false);                          \
        uint32_t shi = (uint32_t)__builtin_amdgcn_update_dpp(                   \
            -1, (int)hi, (CTRL), (RMASK), 0xF, false);                          \
        bool lt = (shi < hi) || ((shi == hi) && (slo < lo));                    \
        lo = lt ? slo : lo;                                                     \
        hi = lt ? shi : hi;                                                     \
    }
    DPP_STEP(0x111, 0xF);  // row_shr:1
    DPP_STEP(0x112, 0xF);  // row_shr:2
    DPP_STEP(0x114, 0xF);  // row_shr:4
    DPP_STEP(0x118, 0xF);  // row_shr:8  -> lane 15/31/47/63 = row min
    DPP_STEP(0x142, 0xA);  // row_bcast:15 -> lane 31 = min(0..31), 63 = min(32..63)
    DPP_STEP(0x143, 0xC);  // row_bcast:31 -> lane 63 = global min
#undef DPP_STEP
    uint32_t glo = (uint32_t)__builtin_amdgcn_readlane((int)lo, 63);
    uint32_t ghi = (uint32_t)__builtin_amdgcn_readlane((int)hi, 63);
    return ((uint64_t)ghi << 32) | glo;
}

__global__ __launch_bounds__(THREADS, 2) void knn_kernel(
    const float* __restrict__ points, int* __restrict__ out)
{
    const int tid = threadIdx.x;
    const int wave = tid >> 6;
    const int lane = tid & 63;
    const int q = blockIdx.x * 2 + wave;   // 1 wave = 1 query
    const int b = q >> 11;                 // N = 2048
    const int n = q & (NPTS - 1);
    const float* bp = points + (size_t)b * NPTS * DIMS;

    // ---- query -> registers (broadcast loads) ----
    float qp[DIMS];
    {
        const float4* qp4 = (const float4*)(bp + (size_t)n * DIMS);
#pragma unroll
        for (int v = 0; v < 4; ++v) {
            float4 t = qp4[v];
            qp[4 * v + 0] = t.x; qp[4 * v + 1] = t.y;
            qp[4 * v + 2] = t.z; qp[4 * v + 3] = t.w;
        }
    }

    // ---- distance phase: 32 candidates/lane, keys straight to registers ----
    uint64_t k[CPL];
#pragma unroll 4
    for (int j = 0; j < CPL; ++j) {
        const int c = lane + (j << 6);     // coalesced across lanes
        const float4* cp4 = (const float4*)(bp + (size_t)c * DIMS);
        float s[DIMS];
#pragma unroll
        for (int v = 0; v < 4; ++v) {
            float4 t = cp4[v];
            float d0 = qp[4 * v + 0] - t.x;
            float d1 = qp[4 * v + 1] - t.y;
            float d2_ = qp[4 * v + 2] - t.z;
            float d3 = qp[4 * v + 3] - t.w;
            s[4 * v + 0] = __fmul_rn(d0, d0);
            s[4 * v + 1] = __fmul_rn(d1, d1);
            s[4 * v + 2] = __fmul_rn(d2_, d2_);
            s[4 * v + 3] = __fmul_rn(d3, d3);
        }
        float r0 = __fadd_rn(s[0], s[8]);
        float r1 = __fadd_rn(s[1], s[9]);
        float r2 = __fadd_rn(s[2], s[10]);
        float r3 = __fadd_rn(s[3], s[11]);
        float r4 = __fadd_rn(s[4], s[12]);
        float r5 = __fadd_rn(s[5], s[13]);
        float r6 = __fadd_rn(s[6], s[14]);
        float r7 = __fadd_rn(s[7], s[15]);
        float t0 = __fadd_rn(r0, r1);
        float t1 = __fadd_rn(r2, r3);
        float t2 = __fadd_rn(r4, r5);
        float t3 = __fadd_rn(r6, r7);
        float d2 = __fadd_rn(__fadd_rn(t0, t1), __fadd_rn(t2, t3));
        float dist = __fsqrt_rn(d2);
        uint64_t key = ((uint64_t)__float_as_uint(dist) << 32) | (uint32_t)c;
        k[j] = (c == n) ? ~0ull : key;     // drop self pre-selection
    }

    // ---- 4 sorted runs of 8 (Batcher odd-even merge, 19 CEs each) ----
#pragma unroll
    for (int r = 0; r < 4; ++r) {
        uint64_t* p = k + r * 8;
        ce(p[0], p[1]); ce(p[2], p[3]); ce(p[4], p[5]); ce(p[6], p[7]);
        ce(p[0], p[2]); ce(p[1], p[3]); ce(p[4], p[6]); ce(p[5], p[7]);
        ce(p[1], p[2]); ce(p[5], p[6]);
        ce(p[0], p[4]); ce(p[1], p[5]); ce(p[2], p[6]); ce(p[3], p[7]);
        ce(p[1], p[4]); ce(p[3], p[6]);
        ce(p[2], p[4]); ce(p[3], p[5]);
        ce(p[3], p[4]);
    }

    // ---- 16 pop rounds; pop r = neighbor rank r ----
    for (int r = 0; r < KK; ++r) {
        uint64_t m = k[0]; int hm = 0;
        if (k[8]  < m) { m = k[8];  hm = 1; }
        if (k[16] < m) { m = k[16]; hm = 2; }
        if (k[24] < m) { m = k[24]; hm = 3; }
        const uint64_t g = wave_min_u64(m);
        if (m == g) {                      // unique winner lane (keys unique)
            int2 val;
            val.x = b;
            val.y = (int)(uint32_t)(g & 0xffffffffu);
            *(int2*)(out + (((size_t)q * KK) + (size_t)r) * 2) = val;
            if (hm == 0) {
#pragma unroll
                for (int j = 0; j < 7; ++j) k[j] = k[j + 1];
                k[7] = ~0ull;
            } else if (hm == 1) {
#pragma unroll
                for (int j = 8; j < 15; ++j) k[j] = k[j + 1];
                k[15] = ~0ull;
            } else if (hm == 2) {
#pragma unroll
                for (int j = 16; j < 23; ++j) k[j] = k[j + 1];
                k[23] = ~0ull;
            } else {
#pragma unroll
                for (int j = 24; j < 31; ++j) k[j] = k[j + 1];
                k[31] = ~0ull;
            }
        }
    }
}

extern "C" void kernel_launch(void* const* d_in, const int* in_sizes, int n_in,
                              void* d_out, int out_size, void* d_ws, size_t ws_size,
                              hipStream_t stream) {
    (void)d_ws; (void)ws_size; (void)out_size;
    // setup_inputs order: {'features', 'points'}; pick points by size (2*2048*16).
    const float* points;
    if (n_in >= 2 && in_sizes[1] == 2 * 2048 * 16) {
        points = (const float*)d_in[1];
    } else if (n_in >= 1 && in_sizes[0] == 2 * 2048 * 16) {
        points = (const float*)d_in[0];
    } else {
        points = (const float*)d_in[n_in - 1];
    }
    int* out = (int*)d_out;
    knn_kernel<<<(2 * 2048) / 2, THREADS, 0, stream>>>(points, out);
}

// Round 7
// 93.186 us; speedup vs baseline: 1.3233x; 1.3233x over previous
//
#include <hip/hip_runtime.h>
#include <stdint.h>

// kNN: B=2, N=2048, D=16, K=16. Output (B,N,K,2) int32: [batch_idx, neighbor_idx].
//
// Bit-exact vs numpy f32 reference — ONLY via named intrinsics
// (__fmul_rn/__fadd_rn/__fsqrt_rn), opaque to -ffp-contract=fast and
// reassociation. (R5 failed with plain FP operators: contraction reordered
// near-tie ranks.) Pairwise tree n=16: r[j]=s[j]+s[j+8];
// ((r0+r1)+(r2+r3))+((r4+r5)+(r6+r7)). __fsqrt_rn == np.sqrt.
// key = (dist_bits<<32)|idx : monotone, ties -> lower index (stable top_k).
// Self (c==n, unique global min) masked pre-selection == [:, :, 1:] slice.
//
// R7 = R6 with the scratch-demotion bug fixed:
//   R6 used `#pragma unroll 4` on the 32-iter distance loop -> j stayed a
//   runtime var -> k[j] dynamic index -> alloca NOT SROA'd -> whole key
//   array lived in scratch (VGPR_Count=52, WRITE_SIZE=145 MB, 72 us).
//   EVERY k[] access must be a compile-time constant index: the distance
//   loop is now FULLY unrolled. Do not reintroduce partial unrolls here.
//
// Structure: 1 wave = 1 query (128-thread block = 2 independent queries).
// NO LDS, NO barriers. 32 candidates/lane -> 32 u64 keys in VGPRs (64 VGPRs;
// __launch_bounds__(128,2) gives a 256-VGPR budget). 4 sorted runs of 8
// (Batcher, 19 CEs), 16 pop rounds: 4-head argmin + DPP wave-min (validated
// R4) + winner-lane run shift + direct int2 store.

#define NPTS 2048
#define DIMS 16
#define KK 16
#define THREADS 128            // 2 waves = 2 independent queries per block
#define CPL 32                 // candidates per lane (2048 / 64)

__device__ __forceinline__ void ce(uint64_t& a, uint64_t& b) {
    uint64_t lo = (a < b) ? a : b;
    uint64_t hi = (a < b) ? b : a;
    a = lo; b = hi;
}

// 64-lane u64 min-reduce via DPP; result broadcast to all lanes via readlane.
// (bit-validated in R4: absmax=0)
__device__ __forceinline__ uint64_t wave_min_u64(uint64_t v) {
    uint32_t lo = (uint32_t)v;
    uint32_t hi = (uint32_t)(v >> 32);
#define DPP_STEP(CTRL, RMASK)                                                   \
    {                                                                           \
        uint32_t slo = (uint32_t)__builtin_amdgcn_update_dpp(                   \
            -1, (int)lo, (CTRL), (RMASK), 0xF, false);                          \
        uint32_t shi = (uint32_t)__builtin_amdgcn_update_dpp(                   \
            -1, (int)hi, (CTRL), (RMASK), 0xF, false);                          \
        bool lt = (shi < hi) || ((shi == hi) && (slo < lo));                    \
        lo = lt ? slo : lo;                                                     \
        hi = lt ? shi : hi;                                                     \
    }
    DPP_STEP(0x111, 0xF);  // row_shr:1
    DPP_STEP(0x112, 0xF);  // row_shr:2
    DPP_STEP(0x114, 0xF);  // row_shr:4
    DPP_STEP(0x118, 0xF);  // row_shr:8  -> lane 15/31/47/63 = row min
    DPP_STEP(0x142, 0xA);  // row_bcast:15 -> lane 31 = min(0..31), 63 = min(32..63)
    DPP_STEP(0x143, 0xC);  // row_bcast:31 -> lane 63 = global min
#undef DPP_STEP
    uint32_t glo = (uint32_t)__builtin_amdgcn_readlane((int)lo, 63);
    uint32_t ghi = (uint32_t)__builtin_amdgcn_readlane((int)hi, 63);
    return ((uint64_t)ghi << 32) | glo;
}

__global__ __launch_bounds__(THREADS, 2) void knn_kernel(
    const float* __restrict__ points, int* __restrict__ out)
{
    const int tid = threadIdx.x;
    const int wave = tid >> 6;
    const int lane = tid & 63;
    const int q = blockIdx.x * 2 + wave;   // 1 wave = 1 query
    const int b = q >> 11;                 // N = 2048
    const int n = q & (NPTS - 1);
    const float* bp = points + (size_t)b * NPTS * DIMS;

    // ---- query -> registers (broadcast loads) ----
    float qp[DIMS];
    {
        const float4* qp4 = (const float4*)(bp + (size_t)n * DIMS);
#pragma unroll
        for (int v = 0; v < 4; ++v) {
            float4 t = qp4[v];
            qp[4 * v + 0] = t.x; qp[4 * v + 1] = t.y;
            qp[4 * v + 2] = t.z; qp[4 * v + 3] = t.w;
        }
    }

    // ---- distance phase: 32 candidates/lane, FULLY unrolled so every k[]
    //      index is constant (SROA -> registers; see header comment) ----
    uint64_t k[CPL];
#pragma unroll
    for (int j = 0; j < CPL; ++j) {
        const int c = lane + (j << 6);     // coalesced across lanes
        const float4* cp4 = (const float4*)(bp + (size_t)c * DIMS);
        float s[DIMS];
#pragma unroll
        for (int v = 0; v < 4; ++v) {
            float4 t = cp4[v];
            float d0 = qp[4 * v + 0] - t.x;
            float d1 = qp[4 * v + 1] - t.y;
            float d2_ = qp[4 * v + 2] - t.z;
            float d3 = qp[4 * v + 3] - t.w;
            s[4 * v + 0] = __fmul_rn(d0, d0);
            s[4 * v + 1] = __fmul_rn(d1, d1);
            s[4 * v + 2] = __fmul_rn(d2_, d2_);
            s[4 * v + 3] = __fmul_rn(d3, d3);
        }
        float r0 = __fadd_rn(s[0], s[8]);
        float r1 = __fadd_rn(s[1], s[9]);
        float r2 = __fadd_rn(s[2], s[10]);
        float r3 = __fadd_rn(s[3], s[11]);
        float r4 = __fadd_rn(s[4], s[12]);
        float r5 = __fadd_rn(s[5], s[13]);
        float r6 = __fadd_rn(s[6], s[14]);
        float r7 = __fadd_rn(s[7], s[15]);
        float t0 = __fadd_rn(r0, r1);
        float t1 = __fadd_rn(r2, r3);
        float t2 = __fadd_rn(r4, r5);
        float t3 = __fadd_rn(r6, r7);
        float d2 = __fadd_rn(__fadd_rn(t0, t1), __fadd_rn(t2, t3));
        float dist = __fsqrt_rn(d2);
        uint64_t key = ((uint64_t)__float_as_uint(dist) << 32) | (uint32_t)c;
        k[j] = (c == n) ? ~0ull : key;     // drop self pre-selection
    }

    // ---- 4 sorted runs of 8 (Batcher odd-even merge, 19 CEs each) ----
#pragma unroll
    for (int r = 0; r < 4; ++r) {
        uint64_t* p = k + r * 8;           // r is a constant after unroll
        ce(p[0], p[1]); ce(p[2], p[3]); ce(p[4], p[5]); ce(p[6], p[7]);
        ce(p[0], p[2]); ce(p[1], p[3]); ce(p[4], p[6]); ce(p[5], p[7]);
        ce(p[1], p[2]); ce(p[5], p[6]);
        ce(p[0], p[4]); ce(p[1], p[5]); ce(p[2], p[6]); ce(p[3], p[7]);
        ce(p[1], p[4]); ce(p[3], p[6]);
        ce(p[2], p[4]); ce(p[3], p[5]);
        ce(p[3], p[4]);
    }

    // ---- 16 pop rounds; pop r = neighbor rank r ----
    for (int r = 0; r < KK; ++r) {
        uint64_t m = k[0]; int hm = 0;
        if (k[8]  < m) { m = k[8];  hm = 1; }
        if (k[16] < m) { m = k[16]; hm = 2; }
        if (k[24] < m) { m = k[24]; hm = 3; }
        const uint64_t g = wave_min_u64(m);
        if (m == g) {                      // unique winner lane (keys unique)
            int2 val;
            val.x = b;
            val.y = (int)(uint32_t)(g & 0xffffffffu);
            *(int2*)(out + (((size_t)q * KK) + (size_t)r) * 2) = val;
            if (hm == 0) {
#pragma unroll
                for (int j = 0; j < 7; ++j) k[j] = k[j + 1];
                k[7] = ~0ull;
            } else if (hm == 1) {
#pragma unroll
                for (int j = 8; j < 15; ++j) k[j] = k[j + 1];
                k[15] = ~0ull;
            } else if (hm == 2) {
#pragma unroll
                for (int j = 16; j < 23; ++j) k[j] = k[j + 1];
                k[23] = ~0ull;
            } else {
#pragma unroll
                for (int j = 24; j < 31; ++j) k[j] = k[j + 1];
                k[31] = ~0ull;
            }
        }
    }
}

extern "C" void kernel_launch(void* const* d_in, const int* in_sizes, int n_in,
                              void* d_out, int out_size, void* d_ws, size_t ws_size,
                              hipStream_t stream) {
    (void)d_ws; (void)ws_size; (void)out_size;
    // setup_inputs order: {'features', 'points'}; pick points by size (2*2048*16).
    const float* points;
    if (n_in >= 2 && in_sizes[1] == 2 * 2048 * 16) {
        points = (const float*)d_in[1];
    } else if (n_in >= 1 && in_sizes[0] == 2 * 2048 * 16) {
        points = (const float*)d_in[0];
    } else {
        points = (const float*)d_in[n_in - 1];
    }
    int* out = (int*)d_out;
    knn_kernel<<<(2 * 2048) / 2, THREADS, 0, stream>>>(points, out);
}